// Round 1
// baseline (76414.038 us; speedup 1.0000x reference)
//
#include <hip/hip_runtime.h>

// ShapeWeaverDecoder: 2-layer LSTM decoder, T=2048 sequential steps, B=32, U=256.
// Design: 64 workgroups, each owns 4 units of layer1 AND layer2 (16 z-columns per
// layer). Weights live in LDS (fp32, ~50KB). The 32 batch chains are pipelined:
// wave v (of 16) owns batches {2v, 2v+1}. Per step: stage1 (z1 -> h1,c1), stage2
// (z2 -> h2,c2). h1/h2 are exchanged across WGs through LLC (agent-scope atomics)
// via 4-deep rings in d_ws, with monotonic per-(batch,wg) flags. No __syncthreads
// in the main loop (all LDS working buffers are wave-private).

#define TSTEPS 2048
#define UNITS  256
#define NB     32
#define NWG    64
#define NTHR   1024

constexpr int WROW = 66;                 // padded LDS row stride (floats) per (col,chunk)
constexpr int WMAT = 64 * WROW;          // one 256x16 weight slice = 4224 floats
constexpr int OFF_W1   = 0;
constexpr int OFF_W2K  = WMAT;
constexpr int OFF_W2R  = 2 * WMAT;
constexpr int OFF_BUFA = 3 * WMAT;                     // 16 waves * [4][WROW]
constexpr int OFF_BUFB = OFF_BUFA + 16 * 4 * WROW;     // 16 waves * 2 slots * [4][WROW]
constexpr int OFF_C1   = OFF_BUFB + 16 * 2 * 4 * WROW; // [32][4]
constexpr int OFF_C2   = OFF_C1 + NB * 4;
constexpr int OFF_WO   = OFF_C2 + NB * 4;              // [256][2]
constexpr int OFF_K1   = OFF_WO + UNITS * 2;           // [2][16]
constexpr int OFF_B1   = OFF_K1 + 32;
constexpr int OFF_B2   = OFF_B1 + 16;
constexpr int OFF_BO   = OFF_B2 + 16;
constexpr int SMEM_FLOATS = OFF_BO + 8;
static_assert(SMEM_FLOATS * 4 < 150 * 1024, "LDS budget");

__device__ __forceinline__ float sigm(float x) { return 1.f / (1.f + expf(-x)); }

__device__ __forceinline__ float aload(const float* p) {
  return __hip_atomic_load(const_cast<float*>(p), __ATOMIC_RELAXED, __HIP_MEMORY_SCOPE_AGENT);
}
__device__ __forceinline__ int aloadi(const int* p) {
  return __hip_atomic_load(const_cast<int*>(p), __ATOMIC_RELAXED, __HIP_MEMORY_SCOPE_AGENT);
}
__device__ __forceinline__ void astore(float* p, float v) {
  __hip_atomic_store(p, v, __ATOMIC_RELAXED, __HIP_MEMORY_SCOPE_AGENT);
}
__device__ __forceinline__ void astorei(int* p, int v) {
  __hip_atomic_store(p, v, __ATOMIC_RELAXED, __HIP_MEMORY_SCOPE_AGENT);
}

// Wait until all 64 per-WG flags (one per lane) reach target. Bounded so a logic
// bug degrades to wrong-but-terminating instead of a hang.
__device__ __forceinline__ bool spin_ge(const int* flags, int lane, int target, bool prev_ok) {
  if (!prev_ok) return false;
  int guard = 0;
  while (true) {
    const int f = aloadi(flags + lane);
    if (__all(f >= target)) break;
    if (++guard > (1 << 20)) return false;
    __builtin_amdgcn_s_sleep(1);
  }
  asm volatile("" ::: "memory");
  return true;
}

__global__ __launch_bounds__(NTHR) void swd_kernel(
    const float* __restrict__ ctx, const float* __restrict__ Wc, const float* __restrict__ bc,
    const float* __restrict__ K1, const float* __restrict__ R1, const float* __restrict__ b1,
    const float* __restrict__ K2, const float* __restrict__ R2, const float* __restrict__ b2,
    const float* __restrict__ Wo, const float* __restrict__ bo,
    float* __restrict__ dout,
    int* __restrict__ flag1, int* __restrict__ flag2,
    float* __restrict__ ring1, float* __restrict__ ring2)
{
  extern __shared__ float sm[];
  const int tid  = threadIdx.x;
  const int wg   = blockIdx.x;
  const int lane = tid & 63;
  const int wid  = tid >> 6;

  // ---- stage weight slices into LDS (one-time) ----
  for (int e = tid; e < 64 * 64; e += NTHR) {
    const int rr = e >> 6, j = e & 63;
    const int cc = rr >> 2, k = rr & 3;
    const int gc = (cc >> 2) * UNITS + wg * 4 + (cc & 3); // keras gate-major column
    const int u  = 64 * k + j;
    sm[OFF_W1  + rr * WROW + j] = R1[u * 1024 + gc];
    sm[OFF_W2K + rr * WROW + j] = K2[u * 1024 + gc];
    sm[OFF_W2R + rr * WROW + j] = R2[u * 1024 + gc];
  }
  for (int e = tid; e < UNITS * 2; e += NTHR) sm[OFF_WO + e] = Wo[e];
  if (tid < 32) {
    const int i = tid >> 4, cc = tid & 15;
    const int gc = (cc >> 2) * UNITS + wg * 4 + (cc & 3);
    sm[OFF_K1 + tid] = K1[i * 1024 + gc];
  }
  if (tid < 16) {
    const int gc = (tid >> 2) * UNITS + wg * 4 + (tid & 3);
    sm[OFF_B1 + tid] = b1[gc];
    sm[OFF_B2 + tid] = b2[gc];
  }
  if (tid < 2) sm[OFF_BO + tid] = bo[tid];
  for (int e = tid; e < NB * 4; e += NTHR) { sm[OFF_C1 + e] = 0.f; sm[OFF_C2 + e] = 0.f; }
  __syncthreads();

  // ---- init: h1[0] = relu(ctx @ Wc + bc) slice, published to ring1 slot 0 ----
  for (int bi = 0; bi < 2; ++bi) {
    const int b = wid * 2 + bi;
    for (int uu = 0; uu < 4; ++uu) {
      float p = 0.f;
      const float* cb = ctx + b * 512;
      const float* wc = Wc + (wg * 4 + uu);
      #pragma unroll
      for (int m = 0; m < 8; ++m) {
        const int i = lane * 8 + m;
        p = fmaf(cb[i], wc[i * UNITS], p);
      }
      #pragma unroll
      for (int d = 32; d; d >>= 1) p += __shfl_down(p, d);
      if (lane == 0) {
        const float h = fmaxf(p + bc[wg * 4 + uu], 0.f);
        astore(ring1 + b * UNITS + wg * 4 + uu, h);
      }
    }
    asm volatile("s_waitcnt vmcnt(0)" ::: "memory");
    if (lane == 0) astorei(flag1 + b * NWG + wg, 1);
  }

  const int c   = lane & 15;        // local z-column
  const int kk  = lane >> 4;        // 64-unit reduction chunk
  const int rr  = (c * 4 + kk) * WROW;
  const int q   = c >> 2;           // gate index (i,f,g,o)
  const int uu4 = lane & 3;
  float* bufA = sm + OFF_BUFA + wid * (4 * WROW);
  bool ok = true;

  for (int s = 0; s < TSTEPS; ++s) {
    // ================= stage 1: z1 = x@K1 + h1[s]@R1 + b1 =================
    for (int bi = 0; bi < 2; ++bi) {
      const int b = wid * 2 + bi;
      float* bufB = sm + OFF_BUFB + (wid * 2 + bi) * (4 * WROW);
      ok = spin_ge(flag1 + b * NWG, lane, s + 1, ok);
      { // gather h1[s] -> bufA
        const float* src = ring1 + (((s & 3) * NB + b) * UNITS) + lane * 4;
        const float v0 = aload(src), v1 = aload(src + 1), v2 = aload(src + 2), v3 = aload(src + 3);
        float* dst = bufA + kk * WROW + (lane & 15) * 4;
        *(float2*)dst       = make_float2(v0, v1);
        *(float2*)(dst + 2) = make_float2(v2, v3);
      }
      float r20 = 0.f, r21 = 0.f, r22 = 0.f, r23 = 0.f;
      if (s > 0) {
        ok = spin_ge(flag2 + b * NWG, lane, s, ok);
        const float* src = ring2 + (((s & 3) * NB + b) * UNITS) + lane * 4;
        r20 = aload(src); r21 = aload(src + 1); r22 = aload(src + 2); r23 = aload(src + 3);
      }
      { // h2[s] -> bufB (zeros when s==0)
        float* dst = bufB + kk * WROW + (lane & 15) * 4;
        *(float2*)dst       = make_float2(r20, r21);
        *(float2*)(dst + 2) = make_float2(r22, r23);
      }
      // x = out(b, s-1) = sigmoid(h2[s] @ Wo + bo); also store to d_out (wg==b)
      float x0 = 0.5f, x1 = 0.5f;
      if (s > 0) {
        float po0 = 0.f, po1 = 0.f;
        const int ub = lane * 4;
        po0 = fmaf(r20, sm[OFF_WO + (ub + 0) * 2 + 0], po0); po1 = fmaf(r20, sm[OFF_WO + (ub + 0) * 2 + 1], po1);
        po0 = fmaf(r21, sm[OFF_WO + (ub + 1) * 2 + 0], po0); po1 = fmaf(r21, sm[OFF_WO + (ub + 1) * 2 + 1], po1);
        po0 = fmaf(r22, sm[OFF_WO + (ub + 2) * 2 + 0], po0); po1 = fmaf(r22, sm[OFF_WO + (ub + 2) * 2 + 1], po1);
        po0 = fmaf(r23, sm[OFF_WO + (ub + 3) * 2 + 0], po0); po1 = fmaf(r23, sm[OFF_WO + (ub + 3) * 2 + 1], po1);
        #pragma unroll
        for (int d = 32; d; d >>= 1) { po0 += __shfl_xor(po0, d); po1 += __shfl_xor(po1, d); }
        x0 = sigm(po0 + sm[OFF_BO]); x1 = sigm(po1 + sm[OFF_BO + 1]);
        if (wg == b && lane == 0)
          *(float2*)(dout + (b * TSTEPS + (s - 1)) * 2) = make_float2(x0, x1);
      }
      // z1 dot (bank-rotated j blocks)
      float axx = 0.f, ayy = 0.f;
      const float* wrow = sm + OFF_W1 + rr;
      const float* hrow = bufA + kk * WROW;
      #pragma unroll
      for (int blk = 0; blk < 4; ++blk) {
        const int jb = ((q + blk) & 3) * 16;
        #pragma unroll
        for (int jj = 0; jj < 16; jj += 2) {
          const float2 w = *(const float2*)(wrow + jb + jj);
          const float2 h = *(const float2*)(hrow + jb + jj);
          axx = fmaf(w.x, h.x, axx); ayy = fmaf(w.y, h.y, ayy);
        }
      }
      float part = axx + ayy;
      part += __shfl_down(part, 32);
      part += __shfl_down(part, 16);
      const float z   = part + x0 * sm[OFF_K1 + c] + x1 * sm[OFF_K1 + 16 + c] + sm[OFF_B1 + c];
      const float act = (q == 2) ? tanhf(z) : sigm(z);
      const float gi = __shfl(act, uu4),     gf = __shfl(act, 4 + uu4),
                  gg = __shfl(act, 8 + uu4), go = __shfl(act, 12 + uu4);
      if (lane < 4) {
        const float cold = sm[OFF_C1 + b * 4 + lane];
        const float cn = gf * cold + gi * gg;
        const float hn = go * tanhf(cn);
        sm[OFF_C1 + b * 4 + lane] = cn;
        astore(ring1 + ((((s + 1) & 3) * NB + b) * UNITS) + wg * 4 + lane, hn);
      }
      asm volatile("s_waitcnt vmcnt(0)" ::: "memory");
      if (lane == 0) astorei(flag1 + b * NWG + wg, s + 2);
    }
    // ================= stage 2: z2 = h1[s+1]@K2 + h2[s]@R2 + b2 =================
    for (int bi = 0; bi < 2; ++bi) {
      const int b = wid * 2 + bi;
      float* bufB = sm + OFF_BUFB + (wid * 2 + bi) * (4 * WROW);
      ok = spin_ge(flag1 + b * NWG, lane, s + 2, ok);
      { // gather h1[s+1] -> bufA
        const float* src = ring1 + ((((s + 1) & 3) * NB + b) * UNITS) + lane * 4;
        const float v0 = aload(src), v1 = aload(src + 1), v2 = aload(src + 2), v3 = aload(src + 3);
        float* dst = bufA + kk * WROW + (lane & 15) * 4;
        *(float2*)dst       = make_float2(v0, v1);
        *(float2*)(dst + 2) = make_float2(v2, v3);
      }
      float axx = 0.f, ayy = 0.f, bxx = 0.f, byy = 0.f;
      const float* wka = sm + OFF_W2K + rr;
      const float* wra = sm + OFF_W2R + rr;
      const float* ha  = bufA + kk * WROW;
      const float* hb  = bufB + kk * WROW;
      #pragma unroll
      for (int blk = 0; blk < 4; ++blk) {
        const int jb = ((q + blk) & 3) * 16;
        #pragma unroll
        for (int jj = 0; jj < 16; jj += 2) {
          const float2 w1v = *(const float2*)(wka + jb + jj);
          const float2 h1v = *(const float2*)(ha + jb + jj);
          const float2 w2v = *(const float2*)(wra + jb + jj);
          const float2 h2v = *(const float2*)(hb + jb + jj);
          axx = fmaf(w1v.x, h1v.x, axx); ayy = fmaf(w1v.y, h1v.y, ayy);
          bxx = fmaf(w2v.x, h2v.x, bxx); byy = fmaf(w2v.y, h2v.y, byy);
        }
      }
      float part = (axx + ayy) + (bxx + byy);
      part += __shfl_down(part, 32);
      part += __shfl_down(part, 16);
      const float z   = part + sm[OFF_B2 + c];
      const float act = (q == 2) ? tanhf(z) : sigm(z);
      const float gi = __shfl(act, uu4),     gf = __shfl(act, 4 + uu4),
                  gg = __shfl(act, 8 + uu4), go = __shfl(act, 12 + uu4);
      if (lane < 4) {
        const float cold = sm[OFF_C2 + b * 4 + lane];
        const float cn = gf * cold + gi * gg;
        const float hn = go * tanhf(cn);
        sm[OFF_C2 + b * 4 + lane] = cn;
        astore(ring2 + ((((s + 1) & 3) * NB + b) * UNITS) + wg * 4 + lane, hn);
      }
      asm volatile("s_waitcnt vmcnt(0)" ::: "memory");
      if (lane == 0) astorei(flag2 + b * NWG + wg, s + 1);
    }
  }

  // ---- epilogue: out(b, T-1) from h2[T] ----
  if (wg < NB && wid == (wg >> 1)) {
    const int b = wg;
    ok = spin_ge(flag2 + b * NWG, lane, TSTEPS, ok);
    const float* src = ring2 + (((TSTEPS & 3) * NB + b) * UNITS) + lane * 4;
    const float r20 = aload(src), r21 = aload(src + 1), r22 = aload(src + 2), r23 = aload(src + 3);
    float po0 = 0.f, po1 = 0.f;
    const int ub = lane * 4;
    po0 = fmaf(r20, sm[OFF_WO + (ub + 0) * 2 + 0], po0); po1 = fmaf(r20, sm[OFF_WO + (ub + 0) * 2 + 1], po1);
    po0 = fmaf(r21, sm[OFF_WO + (ub + 1) * 2 + 0], po0); po1 = fmaf(r21, sm[OFF_WO + (ub + 1) * 2 + 1], po1);
    po0 = fmaf(r22, sm[OFF_WO + (ub + 2) * 2 + 0], po0); po1 = fmaf(r22, sm[OFF_WO + (ub + 2) * 2 + 1], po1);
    po0 = fmaf(r23, sm[OFF_WO + (ub + 3) * 2 + 0], po0); po1 = fmaf(r23, sm[OFF_WO + (ub + 3) * 2 + 1], po1);
    #pragma unroll
    for (int d = 32; d; d >>= 1) { po0 += __shfl_xor(po0, d); po1 += __shfl_xor(po1, d); }
    if (lane == 0)
      *(float2*)(dout + (b * TSTEPS + TSTEPS - 1) * 2) =
          make_float2(sigm(po0 + sm[OFF_BO]), sigm(po1 + sm[OFF_BO + 1]));
  }
  (void)ok;
}

extern "C" void kernel_launch(void* const* d_in, const int* in_sizes, int n_in,
                              void* d_out, int out_size, void* d_ws, size_t ws_size,
                              hipStream_t stream) {
  (void)in_sizes; (void)n_in; (void)out_size; (void)ws_size;
  const float* ctx = (const float*)d_in[0];
  const float* Wc  = (const float*)d_in[1];
  const float* bc  = (const float*)d_in[2];
  const float* K1  = (const float*)d_in[3];
  const float* R1  = (const float*)d_in[4];
  const float* b1  = (const float*)d_in[5];
  const float* K2  = (const float*)d_in[6];
  const float* R2  = (const float*)d_in[7];
  const float* b2  = (const float*)d_in[8];
  const float* Wo  = (const float*)d_in[9];
  const float* bo  = (const float*)d_in[10];

  char* ws = (char*)d_ws;
  int*   flag1 = (int*)ws;                                   // [NB][NWG]
  int*   flag2 = flag1 + NB * NWG;                           // [NB][NWG]
  float* ring1 = (float*)(ws + 2 * NB * NWG * sizeof(int));  // [4][NB][UNITS]
  float* ring2 = ring1 + 4 * NB * UNITS;                     // [4][NB][UNITS]
  // total ws use: 16 KiB flags + 256 KiB rings = 272 KiB

  hipMemsetAsync(d_ws, 0, 2 * NB * NWG * sizeof(int), stream); // reset flags every launch
  hipFuncSetAttribute((const void*)swd_kernel,
                      hipFuncAttributeMaxDynamicSharedMemorySize, SMEM_FLOATS * 4);
  swd_kernel<<<dim3(NWG), dim3(NTHR), SMEM_FLOATS * 4, stream>>>(
      ctx, Wc, bc, K1, R1, b1, K2, R2, b2, Wo, bo,
      (float*)d_out, flag1, flag2, ring1, ring2);
}

// Round 2
// 28180.194 us; speedup vs baseline: 2.7116x; 2.7116x over previous
//
#include <hip/hip_runtime.h>

// ShapeWeaverDecoder: 2-layer LSTM decoder, T=2048 sequential steps, B=32, U=256.
// Round-2 design: weights in VGPRs, LDS only as a tiny wave-private broadcast
// staging buffer for h-vectors.
//   grid = 256 blocks x 512 threads (8 waves), one block per CU (84KB LDS).
//   blocks [0,128):  layer-1 slices. block = (half, slice): 16 gate-cols = 4 units,
//                    batches [half*16, half*16+16), W1 slice in 64 VGPRs/lane.
//   blocks [128,256): layer-2 slices, K2+R2 slices in 128 VGPRs/lane.
// Lane map (as r1): c = lane&15 (z-col), kk = lane>>4 (64-unit chunk).
// h exchange across blocks through LLC (agent-scope atomics) via 4-deep rings in
// d_ws with monotonic per-(batch,slice) flags. No __syncthreads anywhere.

#define TSTEPS 2048
#define UNITS  256
#define NB     32
#define NSL    64
#define NTHR   512

constexpr int CH   = 72;            // chunk stride (floats) in LDS staging
constexpr int VECF = 4 * CH;        // 288 floats per staged 256-vector
constexpr int BUFW = 2 * 2 * VECF;  // per-wave buffer: 2 batches x 2 vectors
constexpr int SMEM_BYTES = 84 * 1024;  // > 80KB => exactly 1 block/CU

__device__ __forceinline__ float sigm(float x) { return 1.f / (1.f + expf(-x)); }

__device__ __forceinline__ float aload(const float* p) {
  return __hip_atomic_load(const_cast<float*>(p), __ATOMIC_RELAXED, __HIP_MEMORY_SCOPE_AGENT);
}
__device__ __forceinline__ int aloadi(const int* p) {
  return __hip_atomic_load(const_cast<int*>(p), __ATOMIC_RELAXED, __HIP_MEMORY_SCOPE_AGENT);
}
__device__ __forceinline__ void astore(float* p, float v) {
  __hip_atomic_store(p, v, __ATOMIC_RELAXED, __HIP_MEMORY_SCOPE_AGENT);
}
__device__ __forceinline__ void astorei(int* p, int v) {
  __hip_atomic_store(p, v, __ATOMIC_RELAXED, __HIP_MEMORY_SCOPE_AGENT);
}

// Wait until all 64 per-slice flags (one per lane) reach target. Bounded so a
// logic bug degrades to wrong-but-terminating instead of a hang.
__device__ __forceinline__ bool spin_ge(const int* flags, int lane, int target, bool prev_ok) {
  if (!prev_ok) return false;
  int guard = 0;
  while (true) {
    const int f = aloadi(flags + lane);
    if (__all(f >= target)) break;
    if (++guard > (1 << 20)) return false;
    __builtin_amdgcn_s_sleep(1);
  }
  asm volatile("" ::: "memory");
  return true;
}

__global__ __launch_bounds__(NTHR) void swd_kernel(
    const float* __restrict__ ctx, const float* __restrict__ Wc, const float* __restrict__ bc,
    const float* __restrict__ K1, const float* __restrict__ R1, const float* __restrict__ b1,
    const float* __restrict__ K2, const float* __restrict__ R2, const float* __restrict__ b2,
    const float* __restrict__ Wo, const float* __restrict__ bo,
    float* __restrict__ dout,
    int* __restrict__ flag1, int* __restrict__ flag2,
    float* __restrict__ ring1, float* __restrict__ ring2)
{
  extern __shared__ float sm[];
  const int wgid  = blockIdx.x;
  const int layer = wgid >> 7;        // 0: layer-1 blocks, 1: layer-2 blocks
  const int half  = (wgid >> 6) & 1;  // which 16 batches
  const int slice = wgid & 63;        // unit slice (4 units = 16 gate-cols)
  const int tid  = threadIdx.x;
  const int lane = tid & 63;
  const int wid  = tid >> 6;
  const int c  = lane & 15;           // local z-column
  const int kk = lane >> 4;           // 64-unit reduction chunk
  const int q  = c >> 2;              // gate (i,f,g,o)
  const int u  = c & 3;               // unit within slice
  const int gc = q * UNITS + slice * 4 + u;  // keras gate-major column
  float* buf = sm + wid * BUFW;       // wave-private staging
  bool ok = true;

  if (layer == 0) {
    // ---- weights into VGPRs ----
    float w1[64];
    #pragma unroll
    for (int j = 0; j < 64; ++j) w1[j] = R1[(64 * kk + j) * 1024 + gc];
    const float k1a = K1[gc], k1b = K1[1024 + gc], bb1 = b1[gc];
    float wo[8];
    #pragma unroll
    for (int m = 0; m < 4; ++m) {
      wo[2 * m]     = Wo[(4 * lane + m) * 2];
      wo[2 * m + 1] = Wo[(4 * lane + m) * 2 + 1];
    }
    const float bo0 = bo[0], bo1 = bo[1];

    // ---- init: publish H1[0] = relu(ctx @ Wc + bc) slice (ring1 slot 0) ----
    #pragma unroll
    for (int bi = 0; bi < 2; ++bi) {
      const int b = half * 16 + wid * 2 + bi;
      #pragma unroll
      for (int uu = 0; uu < 4; ++uu) {
        float p = 0.f;
        const float* cb = ctx + b * 512;
        const float* wc = Wc + slice * 4 + uu;
        #pragma unroll
        for (int m = 0; m < 8; ++m) {
          const int i = lane * 8 + m;
          p = fmaf(cb[i], wc[i * UNITS], p);
        }
        #pragma unroll
        for (int d = 32; d; d >>= 1) p += __shfl_down(p, d);
        if (lane == 0)
          astore(ring1 + b * UNITS + slice * 4 + uu, fmaxf(p + bc[slice * 4 + uu], 0.f));
      }
      asm volatile("s_waitcnt vmcnt(0)" ::: "memory");
      if (lane == 0) astorei(flag1 + b * NSL + slice, 1);
    }

    float c1a = 0.f, c1b = 0.f;  // cell state (valid on lanes 0-3: unit=lane)
    for (int s = 0; s < TSTEPS; ++s) {
      #pragma unroll
      for (int bi = 0; bi < 2; ++bi) {
        const int b = half * 16 + wid * 2 + bi;
        float& c1 = bi ? c1b : c1a;
        float* bb = buf + bi * 2 * VECF;
        // h1[s]: usually already available (published by L1 peers)
        ok = spin_ge(flag1 + b * NSL, lane, s + 1, ok);
        const float* r1p = ring1 + ((s & 3) * NB + b) * UNITS + lane * 4;
        *(float4*)(bb + kk * CH + 4 * c) =
            make_float4(aload(r1p), aload(r1p + 1), aload(r1p + 2), aload(r1p + 3));
        // h2[s] -> x = out[s-1]
        float x0 = 0.5f, x1 = 0.5f;
        if (s > 0) {
          ok = spin_ge(flag2 + b * NSL, lane, s, ok);
          const float* r2p = ring2 + ((s & 3) * NB + b) * UNITS + lane * 4;
          const float g0 = aload(r2p), g1 = aload(r2p + 1), g2 = aload(r2p + 2), g3 = aload(r2p + 3);
          float po0 = g0 * wo[0] + g1 * wo[2] + g2 * wo[4] + g3 * wo[6];
          float po1 = g0 * wo[1] + g1 * wo[3] + g2 * wo[5] + g3 * wo[7];
          #pragma unroll
          for (int d = 1; d < 64; d <<= 1) { po0 += __shfl_xor(po0, d); po1 += __shfl_xor(po1, d); }
          x0 = sigm(po0 + bo0); x1 = sigm(po1 + bo1);
          if (slice == 0 && lane == 0)
            *(float2*)(dout + (b * TSTEPS + s - 1) * 2) = make_float2(x0, x1);
        }
        // z1 = h1[s] @ R1-slice  (weights in regs; h broadcast-read from LDS)
        float ax = 0.f, ay = 0.f, az = 0.f, aw = 0.f;
        #pragma unroll
        for (int j = 0; j < 16; ++j) {
          const float4 hv = *(const float4*)(bb + kk * CH + 4 * j);
          ax = fmaf(w1[4 * j + 0], hv.x, ax);
          ay = fmaf(w1[4 * j + 1], hv.y, ay);
          az = fmaf(w1[4 * j + 2], hv.z, az);
          aw = fmaf(w1[4 * j + 3], hv.w, aw);
        }
        float part = (ax + ay) + (az + aw);
        part += __shfl_down(part, 16);
        part += __shfl_down(part, 32);
        const float z   = part + x0 * k1a + x1 * k1b + bb1;
        const float act = (q == 2) ? tanhf(z) : sigm(z);
        const float gi = __shfl(act, u),     gf = __shfl(act, 4 + u),
                    gg = __shfl(act, 8 + u), go = __shfl(act, 12 + u);
        if (lane < 4) {
          const float cn = gf * c1 + gi * gg;
          c1 = cn;
          astore(ring1 + (((s + 1) & 3) * NB + b) * UNITS + slice * 4 + lane, go * tanhf(cn));
        }
        asm volatile("s_waitcnt vmcnt(0)" ::: "memory");
        if (lane == 0) astorei(flag1 + b * NSL + slice, s + 2);
      }
    }
    // ---- epilogue: out[T-1] = sigmoid(H2[T] @ Wo + bo), written by slice 0 ----
    if (slice == 0) {
      #pragma unroll
      for (int bi = 0; bi < 2; ++bi) {
        const int b = half * 16 + wid * 2 + bi;
        ok = spin_ge(flag2 + b * NSL, lane, TSTEPS, ok);
        const float* r2p = ring2 + ((TSTEPS & 3) * NB + b) * UNITS + lane * 4;
        const float g0 = aload(r2p), g1 = aload(r2p + 1), g2 = aload(r2p + 2), g3 = aload(r2p + 3);
        float po0 = g0 * wo[0] + g1 * wo[2] + g2 * wo[4] + g3 * wo[6];
        float po1 = g0 * wo[1] + g1 * wo[3] + g2 * wo[5] + g3 * wo[7];
        #pragma unroll
        for (int d = 1; d < 64; d <<= 1) { po0 += __shfl_xor(po0, d); po1 += __shfl_xor(po1, d); }
        if (lane == 0)
          *(float2*)(dout + (b * TSTEPS + TSTEPS - 1) * 2) =
              make_float2(sigm(po0 + bo0), sigm(po1 + bo1));
      }
    }
  } else {
    // ======================= layer-2 blocks =======================
    float wk[64], wr[64];
    #pragma unroll
    for (int j = 0; j < 64; ++j) {
      wk[j] = K2[(64 * kk + j) * 1024 + gc];
      wr[j] = R2[(64 * kk + j) * 1024 + gc];
    }
    const float bb2 = b2[gc];
    float c2a = 0.f, c2b = 0.f;
    for (int s = 0; s < TSTEPS; ++s) {
      #pragma unroll
      for (int bi = 0; bi < 2; ++bi) {
        const int b = half * 16 + wid * 2 + bi;
        float& c2 = bi ? c2b : c2a;
        float* bh1 = buf + bi * 2 * VECF;
        float* bh2 = bh1 + VECF;
        // h2[s]: published by L2 peers one stage ago (usually ready)
        float g0 = 0.f, g1 = 0.f, g2 = 0.f, g3 = 0.f;
        if (s > 0) {
          ok = spin_ge(flag2 + b * NSL, lane, s, ok);
          const float* r2p = ring2 + ((s & 3) * NB + b) * UNITS + lane * 4;
          g0 = aload(r2p); g1 = aload(r2p + 1); g2 = aload(r2p + 2); g3 = aload(r2p + 3);
        }
        *(float4*)(bh2 + kk * CH + 4 * c) = make_float4(g0, g1, g2, g3);
        // h1[s+1]: the later-arriving dependency
        ok = spin_ge(flag1 + b * NSL, lane, s + 2, ok);
        const float* r1p = ring1 + (((s + 1) & 3) * NB + b) * UNITS + lane * 4;
        *(float4*)(bh1 + kk * CH + 4 * c) =
            make_float4(aload(r1p), aload(r1p + 1), aload(r1p + 2), aload(r1p + 3));
        // z2 = h1[s+1] @ K2-slice + h2[s] @ R2-slice
        float ax = 0.f, ay = 0.f, az = 0.f, aw = 0.f;
        #pragma unroll
        for (int j = 0; j < 16; ++j) {
          const float4 h1v = *(const float4*)(bh1 + kk * CH + 4 * j);
          const float4 h2v = *(const float4*)(bh2 + kk * CH + 4 * j);
          ax = fmaf(wk[4 * j + 0], h1v.x, ax);
          ay = fmaf(wk[4 * j + 1], h1v.y, ay);
          az = fmaf(wk[4 * j + 2], h1v.z, az);
          aw = fmaf(wk[4 * j + 3], h1v.w, aw);
          ax = fmaf(wr[4 * j + 0], h2v.x, ax);
          ay = fmaf(wr[4 * j + 1], h2v.y, ay);
          az = fmaf(wr[4 * j + 2], h2v.z, az);
          aw = fmaf(wr[4 * j + 3], h2v.w, aw);
        }
        float part = (ax + ay) + (az + aw);
        part += __shfl_down(part, 16);
        part += __shfl_down(part, 32);
        const float z   = part + bb2;
        const float act = (q == 2) ? tanhf(z) : sigm(z);
        const float gi = __shfl(act, u),     gf = __shfl(act, 4 + u),
                    gg = __shfl(act, 8 + u), go = __shfl(act, 12 + u);
        if (lane < 4) {
          const float cn = gf * c2 + gi * gg;
          c2 = cn;
          astore(ring2 + (((s + 1) & 3) * NB + b) * UNITS + slice * 4 + lane, go * tanhf(cn));
        }
        asm volatile("s_waitcnt vmcnt(0)" ::: "memory");
        if (lane == 0) astorei(flag2 + b * NSL + slice, s + 1);
      }
    }
  }
  (void)ok;
}

extern "C" void kernel_launch(void* const* d_in, const int* in_sizes, int n_in,
                              void* d_out, int out_size, void* d_ws, size_t ws_size,
                              hipStream_t stream) {
  (void)in_sizes; (void)n_in; (void)out_size; (void)ws_size;
  const float* ctx = (const float*)d_in[0];
  const float* Wc  = (const float*)d_in[1];
  const float* bc  = (const float*)d_in[2];
  const float* K1  = (const float*)d_in[3];
  const float* R1  = (const float*)d_in[4];
  const float* b1  = (const float*)d_in[5];
  const float* K2  = (const float*)d_in[6];
  const float* R2  = (const float*)d_in[7];
  const float* b2  = (const float*)d_in[8];
  const float* Wo  = (const float*)d_in[9];
  const float* bo  = (const float*)d_in[10];

  char* ws = (char*)d_ws;
  int*   flag1 = (int*)ws;                                   // [NB][NSL]
  int*   flag2 = flag1 + NB * NSL;                           // [NB][NSL]
  float* ring1 = (float*)(ws + 2 * NB * NSL * sizeof(int));  // [4][NB][UNITS]
  float* ring2 = ring1 + 4 * NB * UNITS;                     // [4][NB][UNITS]
  // ws use: 16 KiB flags + 256 KiB rings = 272 KiB

  hipMemsetAsync(d_ws, 0, 2 * NB * NSL * sizeof(int), stream);  // reset flags
  hipFuncSetAttribute((const void*)swd_kernel,
                      hipFuncAttributeMaxDynamicSharedMemorySize, SMEM_BYTES);
  swd_kernel<<<dim3(256), dim3(NTHR), SMEM_BYTES, stream>>>(
      ctx, Wc, bc, K1, R1, b1, K2, R2, b2, Wo, bo,
      (float*)d_out, flag1, flag2, ring1, ring2);
}